// Round 12
// baseline (590.474 us; speedup 1.0000x reference)
//
#include <hip/hip_runtime.h>
#include <hip/hip_bf16.h>

#define B_   32
#define C_   128
#define HW_  3136   // 56*56

typedef __attribute__((ext_vector_type(8))) short  short8v;
typedef __attribute__((ext_vector_type(4))) float  f32x4;
typedef __attribute__((ext_vector_type(4))) uint   u32x4;

// ---------------- ws layout (bytes) ----------------
// pooled:  [0, 16384)  fp32 [32][128]
// top1:    [16384, 16512) int32
// stats:   [16512, 18560) fp32 sum2/ssq2/sum3/ssq3 [4][128]
// bn:      [18560, 20608) fp32 scale2/bias2/scale3/bias3 [4][128]
// Wb0:     [20608, +294912)  bf16 [9][128co][128ci]
// WbS:     [315520, +294912) bf16 [9][128][128]
// Wb1:     [610432, +819200) bf16 [25][128][128]
// Wb2:     [1429632, +131072) bf16 [128co][512ci]
// Wb3:     [1560704, +131072) bf16 [128co][512ci]
// partial: [1691776, +1835008) fp32 BN-stat partials; ALSO diag scratch
//          (diags write it BEFORE the memset that zeroes it for k_srmhf).
//
// ROUND-12 (DIAGNOSTIC): round-11 config (211.5 us, best) + two ablation
// dispatches that split k_main into phases: k_diag_s = staging only,
// k_diag_m = A-prefetch + ds_read/MFMA tap loop only (garbage LDS, values
// kept live via scratch stores). 1792 blocks each (4x real) so they exceed
// k_main's 97 us and surface in rocprof top-5; phase time ~= dur/4.
// Zero correctness impact: scratch region is memset after diags.

__device__ __forceinline__ ushort f2bf(float f) {
  uint32_t b = __float_as_uint(f);
  return (ushort)((b + 0x7FFF + ((b >> 16) & 1)) >> 16);   // RNE
}

__device__ __forceinline__ uint cvtpk(float lo, float hi) {
  uint r;
  asm("v_cvt_pk_bf16_f32 %0, %1, %2" : "=v"(r) : "v"(lo), "v"(hi));
  return r;
}

template <int CTRL>
__device__ __forceinline__ float dppf(float v) {
  return __int_as_float(__builtin_amdgcn_update_dpp(
      0, __float_as_int(v), CTRL, 0xF, 0xF, true));
}
__device__ __forceinline__ float rsum16(float v) {
  v += dppf<0x128>(v);   // row_ror:8
  v += dppf<0x124>(v);   // row_ror:4
  v += dppf<0x122>(v);   // row_ror:2
  v += dppf<0x121>(v);   // row_ror:1
  return v;
}

// ---------------------------------------------------------------
__global__ void k_pool(const float* __restrict__ x, float* __restrict__ pooled) {
  int blk = blockIdx.x;                       // b*128+c
  const float4* p = (const float4*)(x + (size_t)blk * HW_);
  float s = 0.f;
  for (int i = threadIdx.x; i < 784; i += 256) {
    float4 v = p[i];
    s += v.x + v.y + v.z + v.w;
  }
  for (int off = 32; off; off >>= 1) s += __shfl_down(s, off, 64);
  __shared__ float red[4];
  if ((threadIdx.x & 63) == 0) red[threadIdx.x >> 6] = s;
  __syncthreads();
  if (threadIdx.x == 0)
    pooled[blk] = (red[0] + red[1] + red[2] + red[3]) * (1.f / (float)HW_);
}

__global__ void k_gate(const float* __restrict__ pooled, const float* __restrict__ Wg,
                       int* __restrict__ top1, float* __restrict__ tail) {
  __shared__ int cnt[4];
  int t = threadIdx.x;
  if (t < 4) cnt[t] = 0;
  __syncthreads();
  if (t < B_) {
    float l0 = 0, l1 = 0, l2 = 0, l3 = 0;
    const float* pr = pooled + t * C_;
    for (int c = 0; c < C_; ++c) {
      float p = pr[c];
      l0 += p * Wg[c * 4 + 0];
      l1 += p * Wg[c * 4 + 1];
      l2 += p * Wg[c * 4 + 2];
      l3 += p * Wg[c * 4 + 3];
    }
    float best = l0; int am = 0;
    if (l1 > best) { best = l1; am = 1; }
    if (l2 > best) { best = l2; am = 2; }
    if (l3 > best) { best = l3; am = 3; }
    top1[t] = am;
    atomicAdd(&cnt[am], 1);
    for (int e = 0; e < 4; ++e)
      tail[9 + t * 4 + e] = (e == am ? 1.f : 0.f);
  }
  __syncthreads();
  if (t == 0) {
    float c0 = cnt[0], c1 = cnt[1], c2 = cnt[2], c3 = cnt[3];
    float mean = (c0 + c1 + c2 + c3) * 0.25f;
    float var = ((c0 - mean) * (c0 - mean) + (c1 - mean) * (c1 - mean) +
                 (c2 - mean) * (c2 - mean) + (c3 - mean) * (c3 - mean)) * 0.25f;
    tail[0] = var / (mean * mean + 1e-10f);
    tail[1] = c0; tail[2] = c1; tail[3] = c2; tail[4] = c3;
    tail[5] = c0; tail[6] = c1; tail[7] = c2; tail[8] = c3;
  }
}

// Weights -> bf16 MFMA layouts (merged, r8-r11 proven).
__global__ void k_prep(const float* __restrict__ cd, const float* __restrict__ sh,
                       const float* __restrict__ bayar,
                       const float* __restrict__ W2, const float* __restrict__ W3,
                       short* __restrict__ Wb0, short* __restrict__ WbS,
                       short* __restrict__ Wb1,
                       short* __restrict__ W2b, short* __restrict__ W3b) {
  int tid = blockIdx.x * 256 + threadIdx.x;   // o*128 + i
  if (tid >= C_ * C_) return;
  const float* c9 = cd + (size_t)tid * 9;
  const float* s9 = sh + (size_t)tid * 9;
  float s = 0.f;
#pragma unroll
  for (int k = 0; k < 9; ++k) s += c9[k];
#pragma unroll
  for (int k = 0; k < 9; ++k) {
    float w0 = c9[k] + s9[k] - (k == 4 ? 0.7f * s : 0.f);
    Wb0[(size_t)k * 16384 + tid] = (short)f2bf(w0);
    WbS[(size_t)k * 16384 + tid] = (short)f2bf(s9[k]);
  }
  const float* r = bayar + (size_t)tid * 24;
  float rs = 0.f;
#pragma unroll
  for (int k = 0; k < 24; ++k) rs += r[k];
  float inv = 1.f / rs;
  float k25[25];
#pragma unroll
  for (int k = 0; k < 12; ++k) k25[k] = r[k] * inv;
  k25[12] = -1.f;
#pragma unroll
  for (int k = 0; k < 12; ++k) k25[13 + k] = r[12 + k] * inv;
#pragma unroll
  for (int ky = 0; ky < 3; ++ky)
#pragma unroll
    for (int kx = 0; kx < 3; ++kx)
      k25[(ky + 1) * 5 + (kx + 1)] += s9[ky * 3 + kx];
#pragma unroll
  for (int k = 0; k < 25; ++k) Wb1[(size_t)k * 16384 + tid] = (short)f2bf(k25[k]);

  int co = tid >> 7, c = tid & 127;
  const float* sp = W2 + (size_t)co * 384 + c * 3;
  unsigned long long w2 = (unsigned long long)f2bf(sp[0])
                        | ((unsigned long long)f2bf(sp[1]) << 16)
                        | ((unsigned long long)f2bf(sp[2]) << 32);
  *(unsigned long long*)(W2b + (size_t)co * 512 + c * 4) = w2;
  unsigned long long w3 = ((unsigned long long)f2bf(W3[(size_t)co * 128 + c]) << 48);
  *(unsigned long long*)(W3b + (size_t)co * 512 + c * 4) = w3;
}

// SRM + HF (round-3 proven, unchanged).
__global__ __launch_bounds__(512, 4) void k_srmhf(
    const float* __restrict__ x, const short* __restrict__ W2b,
    const short* __restrict__ W3b, const int* __restrict__ top1,
    float* __restrict__ partial, float* ybuf) {
  __shared__ __align__(16) char zl[65536];
  int orig = blockIdx.x;                      // 1792 = 8 * 224
  int wgid = (orig & 7) * 224 + (orig >> 3);
  int b = wgid / 56, h0 = wgid % 56;
  int t = threadIdx.x;
  int l = t & 63, wv = t >> 6;
  const float* xb = x + (size_t)b * C_ * HW_;

  int w_ = l - 2;
  bool wok = (w_ >= 0) & (w_ < 56);
  bool px_ok = (l >= 2) & (l < 58);

  int xoff[5]; bool rok[5];
#pragma unroll
  for (int dy = 0; dy < 5; ++dy) {
    int hh = h0 - 2 + dy;
    rok[dy] = (hh >= 0) & (hh < 56) & wok;
    xoff[dy] = hh * 56 + w_;
  }

#pragma unroll 2
  for (int c = wv; c < C_; c += 8) {
    const float* xc = xb + (size_t)c * HW_;
    float rr[5];
#pragma unroll
    for (int dy = 0; dy < 5; ++dy) {
      float vv = 0.f;
      if (rok[dy]) vv = xc[xoff[dy]];
      rr[dy] = vv;
    }
    float U  = rr[0] + rr[4] + 2.f * rr[2] - 2.f * (rr[1] + rr[3]);
    float Wv = rr[1] + rr[3] - 2.f * rr[2];
    float Sv = rr[1] + rr[2] + rr[3];
    float T  = rr[2];
    float Um1 = dppf<0x138>(U),   Up1 = dppf<0x130>(U);
    float Um2 = dppf<0x138>(Um1), Up2 = dppf<0x130>(Up1);
    float Wm1 = dppf<0x138>(Wv),  Wp1 = dppf<0x130>(Wv);
    float Tm1 = dppf<0x138>(T),   Tp1 = dppf<0x130>(T);
    float Sm1 = dppf<0x138>(Sv),  Sp1 = dppf<0x130>(Sv);
    float Uh = Um2 + Up2 + 2.f * U - 2.f * (Um1 + Up1);
    float Wh = Wm1 + Wp1 - 2.f * Wv;
    float Th = Tm1 + Tp1 - 2.f * T;
    float Sh = Sm1 + Sv + Sp1;
    float s1 = -0.25f * Wh;
    float s2 = (-1.f / 12.f) * (Uh + 2.f * Wh);
    float s3 = 0.5f * Th;
    float lp = 9.f * T - Sh;
    if (px_ok) {
      int px = l - 2;
      uint32_t lo = (uint32_t)f2bf(fminf(fmaxf(s1, -3.f), 3.f))
                  | ((uint32_t)f2bf(fminf(fmaxf(s2, -3.f), 3.f)) << 16);
      uint32_t hi = (uint32_t)f2bf(fminf(fmaxf(s3, -3.f), 3.f))
                  | ((uint32_t)f2bf(lp) << 16);
      int byte = ((px << 10) + (c << 3)) ^ ((px & 7) << 4);
      *(unsigned long long*)(zl + byte) =
          (unsigned long long)lo | ((unsigned long long)hi << 32);
    }
  }

  int lr = l & 15, lk = l >> 4;
  int co0 = wv * 16;
  f32x4 a2[4], a3[4];
#pragma unroll
  for (int n = 0; n < 4; ++n) {
    a2[n] = (f32x4){0.f, 0.f, 0.f, 0.f};
    a3[n] = (f32x4){0.f, 0.f, 0.f, 0.f};
  }
  const short* pA2 = W2b + (size_t)(co0 + lr) * 512 + lk * 8;
  const short* pA3 = W3b + (size_t)(co0 + lr) * 512 + lk * 8;
  short8v A2a = *(const short8v*)(pA2 + 0);
  short8v A3a = *(const short8v*)(pA3 + 0);
  short8v A2b = *(const short8v*)(pA2 + 32);
  short8v A3b = *(const short8v*)(pA3 + 32);
  __syncthreads();
#pragma unroll
  for (int k0 = 0; k0 < 512; k0 += 64) {
    short8v A2c = A2a, A3c = A3a, A2d = A2b, A3d = A3b;
    if (k0 + 64 < 512) {
      A2a = *(const short8v*)(pA2 + k0 + 64);
      A3a = *(const short8v*)(pA3 + k0 + 64);
      A2b = *(const short8v*)(pA2 + k0 + 96);
      A3b = *(const short8v*)(pA3 + k0 + 96);
    }
#pragma unroll
    for (int nf = 0; nf < 4; ++nf) {
      int px = nf * 16 + lr;
      int byte0 = (px * 1024 + (k0 + lk * 8) * 2) ^ ((px & 7) << 4);
      short8v Bf0 = *(const short8v*)(zl + byte0);
      a2[nf] = __builtin_amdgcn_mfma_f32_16x16x32_bf16(A2c, Bf0, a2[nf], 0, 0, 0);
      a3[nf] = __builtin_amdgcn_mfma_f32_16x16x32_bf16(A3c, Bf0, a3[nf], 0, 0, 0);
      int byte1 = (px * 1024 + (k0 + 32 + lk * 8) * 2) ^ ((px & 7) << 4);
      short8v Bf1 = *(const short8v*)(zl + byte1);
      a2[nf] = __builtin_amdgcn_mfma_f32_16x16x32_bf16(A2d, Bf1, a2[nf], 0, 0, 0);
      a3[nf] = __builtin_amdgcn_mfma_f32_16x16x32_bf16(A3d, Bf1, a3[nf], 0, 0, 0);
    }
  }

  int e = top1[b];
  if (e == 2) {
#pragma unroll
    for (int r = 0; r < 4; ++r) {
      int co = co0 + lk * 4 + r;
      float* yp = ybuf + ((size_t)(b * C_ + co)) * HW_ + h0 * 56;
#pragma unroll
      for (int nf = 0; nf < 4; ++nf) {
        int px = nf * 16 + lr;
        if (px < 56) yp[px] = a2[nf][r];
      }
    }
  } else if (e == 3) {
#pragma unroll
    for (int r = 0; r < 4; ++r) {
      int co = co0 + lk * 4 + r;
      float* yp = ybuf + ((size_t)(b * C_ + co)) * HW_ + h0 * 56;
#pragma unroll
      for (int nf = 0; nf < 4; ++nf) {
        int px = nf * 16 + lr;
        if (px < 56) yp[px] = a3[nf][r];
      }
    }
  }

  float* pb = partial + (size_t)(wgid >> 1) * 512;
#pragma unroll
  for (int r = 0; r < 4; ++r) {
    int co = co0 + lk * 4 + r;
    float s2v = 0.f, q2v = 0.f, s3v = 0.f, q3v = 0.f;
#pragma unroll
    for (int nf = 0; nf < 4; ++nf) {
      int px = nf * 16 + lr;
      float w2 = (px < 56) ? a2[nf][r] : 0.f;
      float w3 = (px < 56) ? a3[nf][r] : 0.f;
      s2v += w2; q2v += w2 * w2;
      s3v += w3; q3v += w3 * w3;
    }
    s2v = rsum16(s2v); q2v = rsum16(q2v);
    s3v = rsum16(s3v); q3v = rsum16(q3v);
    if (lr == 0) {
      atomicAdd(&pb[co], s2v);
      atomicAdd(&pb[128 + co], q2v);
      atomicAdd(&pb[256 + co], s3v);
      atomicAdd(&pb[384 + co], q3v);
    }
  }
}

// Reduce partial[896][512] -> stats[512].
__global__ void k_bn2(const float* __restrict__ partial, float* __restrict__ stats) {
  __shared__ float red[4][64];
  int lane = threadIdx.x & 63, wv = threadIdx.x >> 6;
  int entry = blockIdx.x * 64 + lane;
  float s = 0.f;
  for (int j = 0; j < 224; ++j)
    s += partial[(size_t)(wv * 224 + j) * 512 + entry];
  red[wv][lane] = s;
  __syncthreads();
  if (wv == 0)
    stats[entry] = red[0][lane] + red[1][lane] + red[2][lane] + red[3][lane];
}

__global__ void k_bn(const float* __restrict__ stats,
                     const float* __restrict__ g2, const float* __restrict__ b2,
                     const float* __restrict__ g3, const float* __restrict__ b3,
                     float* __restrict__ bn) {
  int c = threadIdx.x;
  if (c >= 128) return;
  const float n = (float)(B_ * HW_);
  float m2 = stats[c] / n, v2 = stats[128 + c] / n - m2 * m2;
  float sc2 = g2[c] * rsqrtf(v2 + 1e-5f);
  bn[c] = sc2; bn[128 + c] = b2[c] - m2 * sc2;
  float m3 = stats[256 + c] / n, v3 = stats[384 + c] / n - m3 * m3;
  float sc3 = g3[c] * rsqrtf(v3 + 1e-5f);
  bn[256 + c] = sc3; bn[384 + c] = b3[c] - m3 * sc3;
}

// ---------------- MFMA implicit-GEMM conv, phase-ablatable ----------------
// <KS,true,true> = round-6/11 proven path (bit-identical). STAGE/MFMA toggles
// exist ONLY for the diagnostic dispatches.
template <int KS, bool STAGE, bool MFMA>
__device__ __forceinline__ void conv_path(const float* __restrict__ xb,
                                          const short* __restrict__ Wb,
                                          char* ldsb, int h0, int t,
                                          f32x4 (&acc)[4][7]) {
  constexpr int PAD = KS / 2;
  constexpr int RN = 4 + 2 * PAD;       // staged input rows
  constexpr int NPOS = RN * 60;
  constexpr int NTAP = KS * KS;
  int l = t & 63, wv = t >> 6;
  int cg = wv & 1, pg = wv >> 1;
  int lr = l & 15, lk = l >> 4;

  int prow[7], pcol[7];
#pragma unroll
  for (int nf = 0; nf < 7; ++nf) {
    int px = pg * 112 + nf * 16 + lr;   // 0..223
    prow[nf] = px / 56;
    pcol[nf] = px % 56;
  }

  for (int ci0 = 0; ci0 < 128; ci0 += 64) {
    __syncthreads();
    if constexpr (STAGE) {
      for (int idx = t; idx < NPOS * 8; idx += 256) {
        int pos = idx % NPOS;
        int cig = idx / NPOS;
        int row = pos / 60, col = pos % 60;
        int h_in = h0 - PAD + row, w_in = col - 2;
        bool ok = (h_in >= 0) & (h_in < 56) & (w_in >= 0) & (w_in < 56);
        const float* xp = xb + (size_t)(ci0 + cig * 8) * HW_ + h_in * 56 + w_in;
        float f[8];
#pragma unroll
        for (int i2 = 0; i2 < 8; ++i2) f[i2] = ok ? xp[i2 * HW_] : 0.f;
        u32x4 pk;
        pk.x = cvtpk(f[0], f[1]);
        pk.y = cvtpk(f[2], f[3]);
        pk.z = cvtpk(f[4], f[5]);
        pk.w = cvtpk(f[6], f[7]);
        int byte = pos * 128 + cig * 16;
        byte ^= (pos & 7) << 4;
        *(u32x4*)(ldsb + byte) = pk;
      }
    }

    short8v At[8];
    const short* wt0 = Wb + (size_t)(cg * 64 + lr) * 128 + ci0 + lk * 8;
    if constexpr (MFMA) {
      // Preload tap 0 A-fragments BEFORE the barrier (weight-only).
#pragma unroll
      for (int hh = 0; hh < 2; ++hh)
#pragma unroll
        for (int m = 0; m < 4; ++m)
          At[hh * 4 + m] = *(const short8v*)(wt0 + (m * 16) * 128 + hh * 32);
    }
    __syncthreads();

    if constexpr (MFMA) {
      for (int tap = 0; tap < NTAP; ++tap) {
        short8v cur[8];
#pragma unroll
        for (int i = 0; i < 8; ++i) cur[i] = At[i];
        if (tap + 1 < NTAP) {
          const short* wtn = wt0 + (size_t)(tap + 1) * 16384;
#pragma unroll
          for (int hh = 0; hh < 2; ++hh)
#pragma unroll
            for (int m = 0; m < 4; ++m)
              At[hh * 4 + m] = *(const short8v*)(wtn + (m * 16) * 128 + hh * 32);
        }
        int dy = tap / KS, dx = tap % KS;
        int posb[7];
#pragma unroll
        for (int nf = 0; nf < 7; ++nf)
          posb[nf] = (prow[nf] + dy) * 60 + pcol[nf] + dx - PAD + 2;
#pragma unroll
        for (int hh = 0; hh < 2; ++hh) {
          int kb = (hh * 32 + lk * 8) * 2;
#pragma unroll
          for (int nf = 0; nf < 7; ++nf) {
            int byte = (posb[nf] * 128 + kb) ^ ((posb[nf] & 7) << 4);
            short8v bf = *(const short8v*)(ldsb + byte);
            acc[0][nf] = __builtin_amdgcn_mfma_f32_16x16x32_bf16(cur[hh * 4 + 0], bf, acc[0][nf], 0, 0, 0);
            acc[1][nf] = __builtin_amdgcn_mfma_f32_16x16x32_bf16(cur[hh * 4 + 1], bf, acc[1][nf], 0, 0, 0);
            acc[2][nf] = __builtin_amdgcn_mfma_f32_16x16x32_bf16(cur[hh * 4 + 2], bf, acc[2][nf], 0, 0, 0);
            acc[3][nf] = __builtin_amdgcn_mfma_f32_16x16x32_bf16(cur[hh * 4 + 3], bf, acc[3][nf], 0, 0, 0);
          }
        }
      }
    }
  }
}

// ---- diagnostic: staging phase only (KS=5 shape, 1792 blocks = 4x work) ----
__global__ __launch_bounds__(256, 2) void k_diag_s(
    const float* __restrict__ x, const short* __restrict__ Wb1,
    float* __restrict__ scratch) {
  __shared__ __align__(16) char ldsb[61440];
  int orig = blockIdx.x;                 // 1792
  int wgid = orig % 448;
  int b = wgid / 14;
  int h0 = (wgid % 14) * 4;
  int t = threadIdx.x;
  f32x4 acc[4][7];
#pragma unroll
  for (int m = 0; m < 4; ++m)
#pragma unroll
    for (int n = 0; n < 7; ++n) acc[m][n] = (f32x4){0.f, 0.f, 0.f, 0.f};
  conv_path<5, true, false>(x + (size_t)b * C_ * HW_, Wb1, ldsb, h0, t, acc);
  __syncthreads();
  // keep LDS stores live: read back and store to scratch
  float v = *(float*)(ldsb + ((t * 244) & 61436));
  scratch[(size_t)orig * 256 + t] = v;
}

// ---- diagnostic: A-prefetch + ds_read/MFMA tap loop only (garbage LDS) ----
__global__ __launch_bounds__(256, 2) void k_diag_m(
    const float* __restrict__ x, const short* __restrict__ Wb1,
    float* __restrict__ scratch) {
  __shared__ __align__(16) char ldsb[61440];
  int orig = blockIdx.x;                 // 1792
  int wgid = orig % 448;
  int b = wgid / 14;
  int h0 = (wgid % 14) * 4;
  int t = threadIdx.x;
  f32x4 acc[4][7];
#pragma unroll
  for (int m = 0; m < 4; ++m)
#pragma unroll
    for (int n = 0; n < 7; ++n) acc[m][n] = (f32x4){0.f, 0.f, 0.f, 0.f};
  conv_path<5, false, true>(x + (size_t)b * C_ * HW_, Wb1, ldsb, h0, t, acc);
  // keep MFMAs live: reduce acc and store
  float ssum = 0.f;
#pragma unroll
  for (int m = 0; m < 4; ++m)
#pragma unroll
    for (int n = 0; n < 7; ++n)
#pragma unroll
      for (int r = 0; r < 4; ++r) ssum += acc[m][n][r];
  scratch[(size_t)orig * 256 + t] = ssum;
}

// ---------------- real k_main (round-6/11 proven, via <KS,true,true>) ------
__global__ __launch_bounds__(256, 2) void k_main(
    const float* __restrict__ x, const short* __restrict__ Wb0,
    const short* __restrict__ WbS, const short* __restrict__ Wb1,
    const float* __restrict__ bn, const int* __restrict__ top1, float* out) {
  __shared__ __align__(16) char ldsb[61440];
  int orig = blockIdx.x;                       // 448 blocks, bijective XCD swizzle
  int wgid = (orig & 7) * 56 + (orig >> 3);
  int b = wgid / 14;
  int h0 = (wgid % 14) * 4;
  int e = top1[b];
  const float* xb = x + (size_t)b * C_ * HW_;
  int t = threadIdx.x;

  f32x4 acc[4][7];
#pragma unroll
  for (int m = 0; m < 4; ++m)
#pragma unroll
    for (int n = 0; n < 7; ++n) acc[m][n] = (f32x4){0.f, 0.f, 0.f, 0.f};

  if (e == 1) conv_path<5, true, true>(xb, Wb1, ldsb, h0, t, acc);
  else        conv_path<3, true, true>(xb, (e == 0) ? Wb0 : WbS, ldsb, h0, t, acc);

  int l = t & 63, wv = t >> 6;
  int cg = wv & 1, pg = wv >> 1;
  int lr = l & 15, lk = l >> 4;
  bool post = (e >= 2);
  const float* sc = bn + (e == 3 ? 256 : 0);
  const float* bi = sc + 128;
#pragma unroll
  for (int mf = 0; mf < 4; ++mf) {
#pragma unroll
    for (int rr = 0; rr < 4; ++rr) {
      int co = cg * 64 + mf * 16 + lk * 4 + rr;
      float s = post ? sc[co] : 0.f;
      float bb = post ? bi[co] : 0.f;
      float* orow = out + ((size_t)(b * C_ + co)) * HW_;
#pragma unroll
      for (int nf = 0; nf < 7; ++nf) {
        int px = pg * 112 + nf * 16 + lr;
        int rg = px / 56, c = px % 56;
        size_t idx = (size_t)(h0 + rg) * 56 + c;
        float v = acc[mf][nf][rr];
        if (post) v += fmaxf(0.f, s * orow[idx] + bb);
        orow[idx] = v;
      }
    }
  }
}

extern "C" void kernel_launch(void* const* d_in, const int* in_sizes, int n_in,
                              void* d_out, int out_size, void* d_ws, size_t ws_size,
                              hipStream_t stream) {
  const float* x        = (const float*)d_in[0];
  const float* Wg       = (const float*)d_in[1];
  const float* cd_w     = (const float*)d_in[2];
  const float* bayar_w  = (const float*)d_in[3];
  const float* srm_out  = (const float*)d_in[5];
  const float* srm_g    = (const float*)d_in[6];
  const float* srm_b    = (const float*)d_in[7];
  const float* hf_out   = (const float*)d_in[9];
  const float* hf_g     = (const float*)d_in[10];
  const float* hf_b     = (const float*)d_in[11];
  const float* shared_w = (const float*)d_in[12];

  char* wsb      = (char*)d_ws;
  float* pooled  = (float*)wsb;                 // 16384 B
  int*   top1    = (int*)(wsb + 16384);         // 128 B
  float* stats   = (float*)(wsb + 16512);       // 2048 B
  float* bn      = (float*)(wsb + 18560);       // 2048 B
  short* Wb0     = (short*)(wsb + 20608);       // 294912 B
  short* WbS     = (short*)(wsb + 315520);      // 294912 B
  short* Wb1     = (short*)(wsb + 610432);      // 819200 B
  short* Wb2     = (short*)(wsb + 1429632);     // 131072 B
  short* Wb3     = (short*)(wsb + 1560704);     // 131072 B
  float* partial = (float*)(wsb + 1691776);     // 1835008 B (diag scratch too)

  float* out  = (float*)d_out;
  float* tail = out + (size_t)12845056;

  k_pool<<<B_ * C_, 256, 0, stream>>>(x, pooled);
  k_gate<<<1, 64, 0, stream>>>(pooled, Wg, top1, tail);
  k_prep<<<64, 256, 0, stream>>>(cd_w, shared_w, bayar_w, srm_out, hf_out,
                                 Wb0, WbS, Wb1, Wb2, Wb3);
  // ---- diagnostics (scribble into partial; memset below clears it) ----
  k_diag_s<<<1792, 256, 0, stream>>>(x, Wb1, partial);
  k_diag_m<<<1792, 256, 0, stream>>>(x, Wb1, partial);
  // ---------------------------------------------------------------------
  hipMemsetAsync(partial, 0, 1835008, stream);
  k_srmhf<<<1792, 512, 0, stream>>>(x, Wb2, Wb3, top1, partial, out);
  k_bn2<<<8, 256, 0, stream>>>(partial, stats);
  k_bn<<<1, 128, 0, stream>>>(stats, srm_g, srm_b, hf_g, hf_b, bn);
  k_main<<<448, 256, 0, stream>>>(x, Wb0, WbS, Wb1, bn, top1, out);
}

// Round 13
// 192.559 us; speedup vs baseline: 3.0665x; 3.0665x over previous
//
#include <hip/hip_runtime.h>
#include <hip/hip_bf16.h>

#define B_   32
#define C_   128
#define HW_  3136   // 56*56

typedef __attribute__((ext_vector_type(8))) short  short8v;
typedef __attribute__((ext_vector_type(4))) float  f32x4;
typedef __attribute__((ext_vector_type(4))) uint   u32x4;

// ---------------- ws layout (bytes) ----------------
// pooled:  [0, 16384)  fp32 [32][128]
// top1:    [16384, 16512) int32
// stats:   [16512, 18560) fp32 sum2/ssq2/sum3/ssq3 [4][128]
// bn:      [18560, 20608) fp32 scale2/bias2/scale3/bias3 [4][128]
// Wb0:     [20608, +294912)  bf16 conv bank, CONTIGUOUS-FRAG layout (9 taps)
// WbS:     [315520, +294912) bf16 conv bank (9 taps, shared)
// Wb1:     [610432, +819200) bf16 conv bank (25 taps, bayar+shared)
// Wb2:     [1429632, +131072) bf16 [128co][512ci] k=4c+j (srm GEMM A)
// Wb3:     [1560704, +131072) bf16 [128co][512ci] k=4c+3 (hf GEMM A)
// partial: [1691776, +1835008) fp32 [896][512] BN-stat partials
//
// ROUND-13: round-12 ablation proved k_main is BW-bound on the WEIGHT stream:
// MFMA+A-load phase alone = ~86us/448blk (= whole kernel); staging minor.
// Effective weight rate 13.7 B/cy/CU (25% of L2 ceiling) because each A
// wave-load scattered over 16 rows x 64B of [tap][co][ci]. Fix: permute conv
// banks to W[cihalf][tap][cg][frag=hh*4+m][lane][8] so every A-fragment
// wave-load is ONE contiguous 1KB block. Element at (tap,o,i):
//   cihalf=i>>6, hh=(i&63)>>5, lk=(i&31)>>3, e=i&7, cg=o>>6, m=(o&63)>>4,
//   lr=o&15, lane=lk*16+lr  ->  fragment semantics identical to old gather.
// Strides (shorts): elem 1, lane 8, frag 512, cg 4096, tap 8192,
// cihalf NTAP*8192. Sizes unchanged (2*9*8192, 2*25*8192 shorts).

__device__ __forceinline__ ushort f2bf(float f) {
  uint32_t b = __float_as_uint(f);
  return (ushort)((b + 0x7FFF + ((b >> 16) & 1)) >> 16);   // RNE
}

__device__ __forceinline__ uint cvtpk(float lo, float hi) {
  uint r;
  asm("v_cvt_pk_bf16_f32 %0, %1, %2" : "=v"(r) : "v"(lo), "v"(hi));
  return r;
}

template <int CTRL>
__device__ __forceinline__ float dppf(float v) {
  return __int_as_float(__builtin_amdgcn_update_dpp(
      0, __float_as_int(v), CTRL, 0xF, 0xF, true));
}
__device__ __forceinline__ float rsum16(float v) {
  v += dppf<0x128>(v);   // row_ror:8
  v += dppf<0x124>(v);   // row_ror:4
  v += dppf<0x122>(v);   // row_ror:2
  v += dppf<0x121>(v);   // row_ror:1
  return v;
}

// scattered-store address (in shorts) for conv-bank element (tap k, co o, ci i)
__device__ __forceinline__ size_t waddr(int ntap, int k, int o, int i) {
  int cihalf = i >> 6;
  int hh = (i & 63) >> 5;
  int lk = (i & 31) >> 3;
  int e  = i & 7;
  int cg = o >> 6;
  int m  = (o & 63) >> 4;
  int lr = o & 15;
  return (size_t)cihalf * ((size_t)ntap * 8192) + (size_t)k * 8192 +
         (size_t)cg * 4096 + (size_t)(hh * 4 + m) * 512 +
         (size_t)(lk * 16 + lr) * 8 + e;
}

// ---------------------------------------------------------------
__global__ void k_pool(const float* __restrict__ x, float* __restrict__ pooled) {
  int blk = blockIdx.x;                       // b*128+c
  const float4* p = (const float4*)(x + (size_t)blk * HW_);
  float s = 0.f;
  for (int i = threadIdx.x; i < 784; i += 256) {
    float4 v = p[i];
    s += v.x + v.y + v.z + v.w;
  }
  for (int off = 32; off; off >>= 1) s += __shfl_down(s, off, 64);
  __shared__ float red[4];
  if ((threadIdx.x & 63) == 0) red[threadIdx.x >> 6] = s;
  __syncthreads();
  if (threadIdx.x == 0)
    pooled[blk] = (red[0] + red[1] + red[2] + red[3]) * (1.f / (float)HW_);
}

__global__ void k_gate(const float* __restrict__ pooled, const float* __restrict__ Wg,
                       int* __restrict__ top1, float* __restrict__ tail) {
  __shared__ int cnt[4];
  int t = threadIdx.x;
  if (t < 4) cnt[t] = 0;
  __syncthreads();
  if (t < B_) {
    float l0 = 0, l1 = 0, l2 = 0, l3 = 0;
    const float* pr = pooled + t * C_;
    for (int c = 0; c < C_; ++c) {
      float p = pr[c];
      l0 += p * Wg[c * 4 + 0];
      l1 += p * Wg[c * 4 + 1];
      l2 += p * Wg[c * 4 + 2];
      l3 += p * Wg[c * 4 + 3];
    }
    float best = l0; int am = 0;
    if (l1 > best) { best = l1; am = 1; }
    if (l2 > best) { best = l2; am = 2; }
    if (l3 > best) { best = l3; am = 3; }
    top1[t] = am;
    atomicAdd(&cnt[am], 1);
    for (int e = 0; e < 4; ++e)
      tail[9 + t * 4 + e] = (e == am ? 1.f : 0.f);
  }
  __syncthreads();
  if (t == 0) {
    float c0 = cnt[0], c1 = cnt[1], c2 = cnt[2], c3 = cnt[3];
    float mean = (c0 + c1 + c2 + c3) * 0.25f;
    float var = ((c0 - mean) * (c0 - mean) + (c1 - mean) * (c1 - mean) +
                 (c2 - mean) * (c2 - mean) + (c3 - mean) * (c3 - mean)) * 0.25f;
    tail[0] = var / (mean * mean + 1e-10f);
    tail[1] = c0; tail[2] = c1; tail[3] = c2; tail[4] = c3;
    tail[5] = c0; tail[6] = c1; tail[7] = c2; tail[8] = c3;
  }
}

// Weights -> bf16 MFMA layouts. Conv banks now stored in contiguous-frag
// layout via waddr(); srm/hf GEMM banks unchanged.
__global__ void k_prep(const float* __restrict__ cd, const float* __restrict__ sh,
                       const float* __restrict__ bayar,
                       const float* __restrict__ W2, const float* __restrict__ W3,
                       short* __restrict__ Wb0, short* __restrict__ WbS,
                       short* __restrict__ Wb1,
                       short* __restrict__ W2b, short* __restrict__ W3b) {
  int tid = blockIdx.x * 256 + threadIdx.x;   // o*128 + i
  if (tid >= C_ * C_) return;
  int o = tid >> 7, i = tid & 127;
  const float* c9 = cd + (size_t)tid * 9;
  const float* s9 = sh + (size_t)tid * 9;
  float s = 0.f;
#pragma unroll
  for (int k = 0; k < 9; ++k) s += c9[k];
#pragma unroll
  for (int k = 0; k < 9; ++k) {
    float w0 = c9[k] + s9[k] - (k == 4 ? 0.7f * s : 0.f);
    size_t a = waddr(9, k, o, i);
    Wb0[a] = (short)f2bf(w0);
    WbS[a] = (short)f2bf(s9[k]);
  }
  const float* r = bayar + (size_t)tid * 24;
  float rs = 0.f;
#pragma unroll
  for (int k = 0; k < 24; ++k) rs += r[k];
  float inv = 1.f / rs;
  float k25[25];
#pragma unroll
  for (int k = 0; k < 12; ++k) k25[k] = r[k] * inv;
  k25[12] = -1.f;
#pragma unroll
  for (int k = 0; k < 12; ++k) k25[13 + k] = r[12 + k] * inv;
#pragma unroll
  for (int ky = 0; ky < 3; ++ky)
#pragma unroll
    for (int kx = 0; kx < 3; ++kx)
      k25[(ky + 1) * 5 + (kx + 1)] += s9[ky * 3 + kx];
#pragma unroll
  for (int k = 0; k < 25; ++k)
    Wb1[waddr(25, k, o, i)] = (short)f2bf(k25[k]);

  // srm_out_w / hf_out_w -> [co][512], k = 4c+j (j<3 srm, j=3 hf)
  int co = o, c = i;
  const float* sp = W2 + (size_t)co * 384 + c * 3;
  unsigned long long w2 = (unsigned long long)f2bf(sp[0])
                        | ((unsigned long long)f2bf(sp[1]) << 16)
                        | ((unsigned long long)f2bf(sp[2]) << 32);
  *(unsigned long long*)(W2b + (size_t)co * 512 + c * 4) = w2;
  unsigned long long w3 = ((unsigned long long)f2bf(W3[(size_t)co * 128 + c]) << 48);
  *(unsigned long long*)(W3b + (size_t)co * 512 + c * 4) = w3;
}

// SRM + HF (round-3 proven, unchanged).
__global__ __launch_bounds__(512, 4) void k_srmhf(
    const float* __restrict__ x, const short* __restrict__ W2b,
    const short* __restrict__ W3b, const int* __restrict__ top1,
    float* __restrict__ partial, float* ybuf) {
  __shared__ __align__(16) char zl[65536];
  int orig = blockIdx.x;                      // 1792 = 8 * 224
  int wgid = (orig & 7) * 224 + (orig >> 3);
  int b = wgid / 56, h0 = wgid % 56;
  int t = threadIdx.x;
  int l = t & 63, wv = t >> 6;
  const float* xb = x + (size_t)b * C_ * HW_;

  int w_ = l - 2;
  bool wok = (w_ >= 0) & (w_ < 56);
  bool px_ok = (l >= 2) & (l < 58);

  int xoff[5]; bool rok[5];
#pragma unroll
  for (int dy = 0; dy < 5; ++dy) {
    int hh = h0 - 2 + dy;
    rok[dy] = (hh >= 0) & (hh < 56) & wok;
    xoff[dy] = hh * 56 + w_;
  }

#pragma unroll 2
  for (int c = wv; c < C_; c += 8) {
    const float* xc = xb + (size_t)c * HW_;
    float rr[5];
#pragma unroll
    for (int dy = 0; dy < 5; ++dy) {
      float vv = 0.f;
      if (rok[dy]) vv = xc[xoff[dy]];
      rr[dy] = vv;
    }
    float U  = rr[0] + rr[4] + 2.f * rr[2] - 2.f * (rr[1] + rr[3]);
    float Wv = rr[1] + rr[3] - 2.f * rr[2];
    float Sv = rr[1] + rr[2] + rr[3];
    float T  = rr[2];
    float Um1 = dppf<0x138>(U),   Up1 = dppf<0x130>(U);
    float Um2 = dppf<0x138>(Um1), Up2 = dppf<0x130>(Up1);
    float Wm1 = dppf<0x138>(Wv),  Wp1 = dppf<0x130>(Wv);
    float Tm1 = dppf<0x138>(T),   Tp1 = dppf<0x130>(T);
    float Sm1 = dppf<0x138>(Sv),  Sp1 = dppf<0x130>(Sv);
    float Uh = Um2 + Up2 + 2.f * U - 2.f * (Um1 + Up1);
    float Wh = Wm1 + Wp1 - 2.f * Wv;
    float Th = Tm1 + Tp1 - 2.f * T;
    float Sh = Sm1 + Sv + Sp1;
    float s1 = -0.25f * Wh;
    float s2 = (-1.f / 12.f) * (Uh + 2.f * Wh);
    float s3 = 0.5f * Th;
    float lp = 9.f * T - Sh;
    if (px_ok) {
      int px = l - 2;
      uint32_t lo = (uint32_t)f2bf(fminf(fmaxf(s1, -3.f), 3.f))
                  | ((uint32_t)f2bf(fminf(fmaxf(s2, -3.f), 3.f)) << 16);
      uint32_t hi = (uint32_t)f2bf(fminf(fmaxf(s3, -3.f), 3.f))
                  | ((uint32_t)f2bf(lp) << 16);
      int byte = ((px << 10) + (c << 3)) ^ ((px & 7) << 4);
      *(unsigned long long*)(zl + byte) =
          (unsigned long long)lo | ((unsigned long long)hi << 32);
    }
  }

  int lr = l & 15, lk = l >> 4;
  int co0 = wv * 16;
  f32x4 a2[4], a3[4];
#pragma unroll
  for (int n = 0; n < 4; ++n) {
    a2[n] = (f32x4){0.f, 0.f, 0.f, 0.f};
    a3[n] = (f32x4){0.f, 0.f, 0.f, 0.f};
  }
  const short* pA2 = W2b + (size_t)(co0 + lr) * 512 + lk * 8;
  const short* pA3 = W3b + (size_t)(co0 + lr) * 512 + lk * 8;
  short8v A2a = *(const short8v*)(pA2 + 0);
  short8v A3a = *(const short8v*)(pA3 + 0);
  short8v A2b = *(const short8v*)(pA2 + 32);
  short8v A3b = *(const short8v*)(pA3 + 32);
  __syncthreads();
#pragma unroll
  for (int k0 = 0; k0 < 512; k0 += 64) {
    short8v A2c = A2a, A3c = A3a, A2d = A2b, A3d = A3b;
    if (k0 + 64 < 512) {
      A2a = *(const short8v*)(pA2 + k0 + 64);
      A3a = *(const short8v*)(pA3 + k0 + 64);
      A2b = *(const short8v*)(pA2 + k0 + 96);
      A3b = *(const short8v*)(pA3 + k0 + 96);
    }
#pragma unroll
    for (int nf = 0; nf < 4; ++nf) {
      int px = nf * 16 + lr;
      int byte0 = (px * 1024 + (k0 + lk * 8) * 2) ^ ((px & 7) << 4);
      short8v Bf0 = *(const short8v*)(zl + byte0);
      a2[nf] = __builtin_amdgcn_mfma_f32_16x16x32_bf16(A2c, Bf0, a2[nf], 0, 0, 0);
      a3[nf] = __builtin_amdgcn_mfma_f32_16x16x32_bf16(A3c, Bf0, a3[nf], 0, 0, 0);
      int byte1 = (px * 1024 + (k0 + 32 + lk * 8) * 2) ^ ((px & 7) << 4);
      short8v Bf1 = *(const short8v*)(zl + byte1);
      a2[nf] = __builtin_amdgcn_mfma_f32_16x16x32_bf16(A2d, Bf1, a2[nf], 0, 0, 0);
      a3[nf] = __builtin_amdgcn_mfma_f32_16x16x32_bf16(A3d, Bf1, a3[nf], 0, 0, 0);
    }
  }

  int e = top1[b];
  if (e == 2) {
#pragma unroll
    for (int r = 0; r < 4; ++r) {
      int co = co0 + lk * 4 + r;
      float* yp = ybuf + ((size_t)(b * C_ + co)) * HW_ + h0 * 56;
#pragma unroll
      for (int nf = 0; nf < 4; ++nf) {
        int px = nf * 16 + lr;
        if (px < 56) yp[px] = a2[nf][r];
      }
    }
  } else if (e == 3) {
#pragma unroll
    for (int r = 0; r < 4; ++r) {
      int co = co0 + lk * 4 + r;
      float* yp = ybuf + ((size_t)(b * C_ + co)) * HW_ + h0 * 56;
#pragma unroll
      for (int nf = 0; nf < 4; ++nf) {
        int px = nf * 16 + lr;
        if (px < 56) yp[px] = a3[nf][r];
      }
    }
  }

  float* pb = partial + (size_t)(wgid >> 1) * 512;
#pragma unroll
  for (int r = 0; r < 4; ++r) {
    int co = co0 + lk * 4 + r;
    float s2v = 0.f, q2v = 0.f, s3v = 0.f, q3v = 0.f;
#pragma unroll
    for (int nf = 0; nf < 4; ++nf) {
      int px = nf * 16 + lr;
      float w2 = (px < 56) ? a2[nf][r] : 0.f;
      float w3 = (px < 56) ? a3[nf][r] : 0.f;
      s2v += w2; q2v += w2 * w2;
      s3v += w3; q3v += w3 * w3;
    }
    s2v = rsum16(s2v); q2v = rsum16(q2v);
    s3v = rsum16(s3v); q3v = rsum16(q3v);
    if (lr == 0) {
      atomicAdd(&pb[co], s2v);
      atomicAdd(&pb[128 + co], q2v);
      atomicAdd(&pb[256 + co], s3v);
      atomicAdd(&pb[384 + co], q3v);
    }
  }
}

// Reduce partial[896][512] -> stats[512].
__global__ void k_bn2(const float* __restrict__ partial, float* __restrict__ stats) {
  __shared__ float red[4][64];
  int lane = threadIdx.x & 63, wv = threadIdx.x >> 6;
  int entry = blockIdx.x * 64 + lane;
  float s = 0.f;
  for (int j = 0; j < 224; ++j)
    s += partial[(size_t)(wv * 224 + j) * 512 + entry];
  red[wv][lane] = s;
  __syncthreads();
  if (wv == 0)
    stats[entry] = red[0][lane] + red[1][lane] + red[2][lane] + red[3][lane];
}

__global__ void k_bn(const float* __restrict__ stats,
                     const float* __restrict__ g2, const float* __restrict__ b2,
                     const float* __restrict__ g3, const float* __restrict__ b3,
                     float* __restrict__ bn) {
  int c = threadIdx.x;
  if (c >= 128) return;
  const float n = (float)(B_ * HW_);
  float m2 = stats[c] / n, v2 = stats[128 + c] / n - m2 * m2;
  float sc2 = g2[c] * rsqrtf(v2 + 1e-5f);
  bn[c] = sc2; bn[128 + c] = b2[c] - m2 * sc2;
  float m3 = stats[256 + c] / n, v3 = stats[384 + c] / n - m3 * m3;
  float sc3 = g3[c] * rsqrtf(v3 + 1e-5f);
  bn[256 + c] = sc3; bn[384 + c] = b3[c] - m3 * sc3;
}

// ---------------- MFMA implicit-GEMM conv (contiguous weight loads) --------
// Each A-fragment wave-load = ONE contiguous 1KB block (was 16 rows x 64B).
// Tap-ahead prefetch retained (round-6). Fragment semantics identical.
template <int KS>
__device__ __forceinline__ void conv_path(const float* __restrict__ xb,
                                          const short* __restrict__ Wb,
                                          char* ldsb, int h0, int t,
                                          f32x4 (&acc)[4][7]) {
  constexpr int PAD = KS / 2;
  constexpr int RN = 4 + 2 * PAD;       // staged input rows
  constexpr int NPOS = RN * 60;
  constexpr int NTAP = KS * KS;
  int l = t & 63, wv = t >> 6;
  int cg = wv & 1, pg = wv >> 1;
  int lr = l & 15, lk = l >> 4;

  int prow[7], pcol[7];
#pragma unroll
  for (int nf = 0; nf < 7; ++nf) {
    int px = pg * 112 + nf * 16 + lr;   // 0..223
    prow[nf] = px / 56;
    pcol[nf] = px % 56;
  }

  for (int ci0 = 0; ci0 < 128; ci0 += 64) {
    __syncthreads();
    for (int idx = t; idx < NPOS * 8; idx += 256) {
      int pos = idx % NPOS;
      int cig = idx / NPOS;
      int row = pos / 60, col = pos % 60;
      int h_in = h0 - PAD + row, w_in = col - 2;
      bool ok = (h_in >= 0) & (h_in < 56) & (w_in >= 0) & (w_in < 56);
      const float* xp = xb + (size_t)(ci0 + cig * 8) * HW_ + h_in * 56 + w_in;
      float f[8];
#pragma unroll
      for (int i2 = 0; i2 < 8; ++i2) f[i2] = ok ? xp[i2 * HW_] : 0.f;
      u32x4 pk;
      pk.x = cvtpk(f[0], f[1]);
      pk.y = cvtpk(f[2], f[3]);
      pk.z = cvtpk(f[4], f[5]);
      pk.w = cvtpk(f[6], f[7]);
      int byte = pos * 128 + cig * 16;
      byte ^= (pos & 7) << 4;
      *(u32x4*)(ldsb + byte) = pk;
    }

    // Contiguous weight base for this (cihalf, cg, lane): frag f at +f*512,
    // tap at +tap*8192 (shorts). Preload tap 0 before the barrier.
    const short* wbase = Wb + (size_t)(ci0 >> 6) * ((size_t)NTAP * 8192) +
                         (size_t)cg * 4096 + (size_t)l * 8;
    short8v At[8];
#pragma unroll
    for (int f = 0; f < 8; ++f)
      At[f] = *(const short8v*)(wbase + f * 512);
    __syncthreads();

    for (int tap = 0; tap < NTAP; ++tap) {
      short8v cur[8];
#pragma unroll
      for (int i = 0; i < 8; ++i) cur[i] = At[i];
      if (tap + 1 < NTAP) {
        const short* wtn = wbase + (size_t)(tap + 1) * 8192;
#pragma unroll
        for (int f = 0; f < 8; ++f)
          At[f] = *(const short8v*)(wtn + f * 512);
      }
      int dy = tap / KS, dx = tap % KS;
      int posb[7];
#pragma unroll
      for (int nf = 0; nf < 7; ++nf)
        posb[nf] = (prow[nf] + dy) * 60 + pcol[nf] + dx - PAD + 2;
#pragma unroll
      for (int hh = 0; hh < 2; ++hh) {
        int kb = (hh * 32 + lk * 8) * 2;
#pragma unroll
        for (int nf = 0; nf < 7; ++nf) {
          int byte = (posb[nf] * 128 + kb) ^ ((posb[nf] & 7) << 4);
          short8v bf = *(const short8v*)(ldsb + byte);
          acc[0][nf] = __builtin_amdgcn_mfma_f32_16x16x32_bf16(cur[hh * 4 + 0], bf, acc[0][nf], 0, 0, 0);
          acc[1][nf] = __builtin_amdgcn_mfma_f32_16x16x32_bf16(cur[hh * 4 + 1], bf, acc[1][nf], 0, 0, 0);
          acc[2][nf] = __builtin_amdgcn_mfma_f32_16x16x32_bf16(cur[hh * 4 + 2], bf, acc[2][nf], 0, 0, 0);
          acc[3][nf] = __builtin_amdgcn_mfma_f32_16x16x32_bf16(cur[hh * 4 + 3], bf, acc[3][nf], 0, 0, 0);
        }
      }
    }
  }
}

__global__ __launch_bounds__(256, 2) void k_main(
    const float* __restrict__ x, const short* __restrict__ Wb0,
    const short* __restrict__ WbS, const short* __restrict__ Wb1,
    const float* __restrict__ bn, const int* __restrict__ top1, float* out) {
  __shared__ __align__(16) char ldsb[61440];
  int orig = blockIdx.x;                       // 448 blocks, bijective XCD swizzle
  int wgid = (orig & 7) * 56 + (orig >> 3);
  int b = wgid / 14;
  int h0 = (wgid % 14) * 4;
  int e = top1[b];
  const float* xb = x + (size_t)b * C_ * HW_;
  int t = threadIdx.x;

  f32x4 acc[4][7];
#pragma unroll
  for (int m = 0; m < 4; ++m)
#pragma unroll
    for (int n = 0; n < 7; ++n) acc[m][n] = (f32x4){0.f, 0.f, 0.f, 0.f};

  if (e == 1) conv_path<5>(xb, Wb1, ldsb, h0, t, acc);
  else        conv_path<3>(xb, (e == 0) ? Wb0 : WbS, ldsb, h0, t, acc);

  int l = t & 63, wv = t >> 6;
  int cg = wv & 1, pg = wv >> 1;
  int lr = l & 15, lk = l >> 4;
  bool post = (e >= 2);
  const float* sc = bn + (e == 3 ? 256 : 0);
  const float* bi = sc + 128;
#pragma unroll
  for (int mf = 0; mf < 4; ++mf) {
#pragma unroll
    for (int rr = 0; rr < 4; ++rr) {
      int co = cg * 64 + mf * 16 + lk * 4 + rr;
      float s = post ? sc[co] : 0.f;
      float bb = post ? bi[co] : 0.f;
      float* orow = out + ((size_t)(b * C_ + co)) * HW_;
#pragma unroll
      for (int nf = 0; nf < 7; ++nf) {
        int px = pg * 112 + nf * 16 + lr;
        int rg = px / 56, c = px % 56;
        size_t idx = (size_t)(h0 + rg) * 56 + c;
        float v = acc[mf][nf][rr];
        if (post) v += fmaxf(0.f, s * orow[idx] + bb);
        orow[idx] = v;
      }
    }
  }
}

extern "C" void kernel_launch(void* const* d_in, const int* in_sizes, int n_in,
                              void* d_out, int out_size, void* d_ws, size_t ws_size,
                              hipStream_t stream) {
  const float* x        = (const float*)d_in[0];
  const float* Wg       = (const float*)d_in[1];
  const float* cd_w     = (const float*)d_in[2];
  const float* bayar_w  = (const float*)d_in[3];
  const float* srm_out  = (const float*)d_in[5];
  const float* srm_g    = (const float*)d_in[6];
  const float* srm_b    = (const float*)d_in[7];
  const float* hf_out   = (const float*)d_in[9];
  const float* hf_g     = (const float*)d_in[10];
  const float* hf_b     = (const float*)d_in[11];
  const float* shared_w = (const float*)d_in[12];

  char* wsb      = (char*)d_ws;
  float* pooled  = (float*)wsb;                 // 16384 B
  int*   top1    = (int*)(wsb + 16384);         // 128 B
  float* stats   = (float*)(wsb + 16512);       // 2048 B
  float* bn      = (float*)(wsb + 18560);       // 2048 B
  short* Wb0     = (short*)(wsb + 20608);       // 294912 B
  short* WbS     = (short*)(wsb + 315520);      // 294912 B
  short* Wb1     = (short*)(wsb + 610432);      // 819200 B
  short* Wb2     = (short*)(wsb + 1429632);     // 131072 B
  short* Wb3     = (short*)(wsb + 1560704);     // 131072 B
  float* partial = (float*)(wsb + 1691776);     // 1835008 B -> ends 3526784

  float* out  = (float*)d_out;
  float* tail = out + (size_t)12845056;

  hipMemsetAsync(partial, 0, 1835008, stream);
  k_pool<<<B_ * C_, 256, 0, stream>>>(x, pooled);
  k_gate<<<1, 64, 0, stream>>>(pooled, Wg, top1, tail);
  k_prep<<<64, 256, 0, stream>>>(cd_w, shared_w, bayar_w, srm_out, hf_out,
                                 Wb0, WbS, Wb1, Wb2, Wb3);
  k_srmhf<<<1792, 512, 0, stream>>>(x, Wb2, Wb3, top1, partial, out);
  k_bn2<<<8, 256, 0, stream>>>(partial, stats);
  k_bn<<<1, 128, 0, stream>>>(stats, srm_g, srm_b, hf_g, hf_b, bn);
  k_main<<<448, 256, 0, stream>>>(x, Wb0, WbS, Wb1, bn, top1, out);
}

// Round 14
// 165.039 us; speedup vs baseline: 3.5778x; 1.1667x over previous
//
#include <hip/hip_runtime.h>
#include <hip/hip_bf16.h>

#define B_   32
#define C_   128
#define HW_  3136   // 56*56

typedef __attribute__((ext_vector_type(8))) short  short8v;
typedef __attribute__((ext_vector_type(4))) float  f32x4;
typedef __attribute__((ext_vector_type(4))) uint   u32x4;

// ---------------- ws layout (bytes) ----------------
// pooled:  [0, 16384)  fp32 [32][128]
// top1:    [16384, 16512) int32
// stats:   [16512, 18560) fp32 sum2/ssq2/sum3/ssq3 [4][128]
// bn:      [18560, 20608) fp32 scale2/bias2/scale3/bias3 [4][128]
// Wb0:     [20608, +294912)  bf16 conv bank, contiguous-frag layout (9 taps)
// WbS:     [315520, +294912) bf16 conv bank (9 taps, shared)
// Wb1:     [610432, +819200) bf16 conv bank (25 taps, bayar+shared)
// Wb2:     [1429632, +131072) bf16 srm GEMM A, contiguous-frag layout
// Wb3:     [1560704, +131072) bf16 hf GEMM A, contiguous-frag layout
// partial: [1691776, +1835008) fp32 [896][512] BN-stat partials
//
// ROUND-14: round-13's contiguous-fragment relayout (k_main 97->~78, proven)
// applied to k_srmhf's GEMM A-streams, which have the identical pathology:
// old [co][512] layout -> wave-load = 16 rows x 64B scattered; at the
// MEASURED scattered rate (13.7 B/cy/CU, r12 diag) the 256KB/block A-traffic
// = ~53us of k_srmhf's 94.6us. New layout [cogrp=co>>4][kblk=k>>5][lane][8]:
// each fragment = ONE contiguous 1KB wave-load; a wave streams 16KB linearly.
// Element (co,k): cogrp*8192 + (k>>5)*512 + ((k&31)>>3*16 + (co&15))*8 + (k&7)
// -> lane l=lk*16+lr slot l*8 holds row co0+lr, k=kblk*32+lk*8+e (identical
// fragment semantics). Also: z-store f2bf x4 -> 2x v_cvt_pk_bf16_f32.

__device__ __forceinline__ ushort f2bf(float f) {
  uint32_t b = __float_as_uint(f);
  return (ushort)((b + 0x7FFF + ((b >> 16) & 1)) >> 16);   // RNE
}

__device__ __forceinline__ uint cvtpk(float lo, float hi) {
  uint r;
  asm("v_cvt_pk_bf16_f32 %0, %1, %2" : "=v"(r) : "v"(lo), "v"(hi));
  return r;
}

template <int CTRL>
__device__ __forceinline__ float dppf(float v) {
  return __int_as_float(__builtin_amdgcn_update_dpp(
      0, __float_as_int(v), CTRL, 0xF, 0xF, true));
}
__device__ __forceinline__ float rsum16(float v) {
  v += dppf<0x128>(v);   // row_ror:8
  v += dppf<0x124>(v);   // row_ror:4
  v += dppf<0x122>(v);   // row_ror:2
  v += dppf<0x121>(v);   // row_ror:1
  return v;
}

// conv-bank scattered-store address (shorts) for element (tap k, co o, ci i)
__device__ __forceinline__ size_t waddr(int ntap, int k, int o, int i) {
  int cihalf = i >> 6;
  int hh = (i & 63) >> 5;
  int lk = (i & 31) >> 3;
  int e  = i & 7;
  int cg = o >> 6;
  int m  = (o & 63) >> 4;
  int lr = o & 15;
  return (size_t)cihalf * ((size_t)ntap * 8192) + (size_t)k * 8192 +
         (size_t)cg * 4096 + (size_t)(hh * 4 + m) * 512 +
         (size_t)(lk * 16 + lr) * 8 + e;
}

// ---------------------------------------------------------------
__global__ void k_pool(const float* __restrict__ x, float* __restrict__ pooled) {
  int blk = blockIdx.x;                       // b*128+c
  const float4* p = (const float4*)(x + (size_t)blk * HW_);
  float s = 0.f;
  for (int i = threadIdx.x; i < 784; i += 256) {
    float4 v = p[i];
    s += v.x + v.y + v.z + v.w;
  }
  for (int off = 32; off; off >>= 1) s += __shfl_down(s, off, 64);
  __shared__ float red[4];
  if ((threadIdx.x & 63) == 0) red[threadIdx.x >> 6] = s;
  __syncthreads();
  if (threadIdx.x == 0)
    pooled[blk] = (red[0] + red[1] + red[2] + red[3]) * (1.f / (float)HW_);
}

__global__ void k_gate(const float* __restrict__ pooled, const float* __restrict__ Wg,
                       int* __restrict__ top1, float* __restrict__ tail) {
  __shared__ int cnt[4];
  int t = threadIdx.x;
  if (t < 4) cnt[t] = 0;
  __syncthreads();
  if (t < B_) {
    float l0 = 0, l1 = 0, l2 = 0, l3 = 0;
    const float* pr = pooled + t * C_;
    for (int c = 0; c < C_; ++c) {
      float p = pr[c];
      l0 += p * Wg[c * 4 + 0];
      l1 += p * Wg[c * 4 + 1];
      l2 += p * Wg[c * 4 + 2];
      l3 += p * Wg[c * 4 + 3];
    }
    float best = l0; int am = 0;
    if (l1 > best) { best = l1; am = 1; }
    if (l2 > best) { best = l2; am = 2; }
    if (l3 > best) { best = l3; am = 3; }
    top1[t] = am;
    atomicAdd(&cnt[am], 1);
    for (int e = 0; e < 4; ++e)
      tail[9 + t * 4 + e] = (e == am ? 1.f : 0.f);
  }
  __syncthreads();
  if (t == 0) {
    float c0 = cnt[0], c1 = cnt[1], c2 = cnt[2], c3 = cnt[3];
    float mean = (c0 + c1 + c2 + c3) * 0.25f;
    float var = ((c0 - mean) * (c0 - mean) + (c1 - mean) * (c1 - mean) +
                 (c2 - mean) * (c2 - mean) + (c3 - mean) * (c3 - mean)) * 0.25f;
    tail[0] = var / (mean * mean + 1e-10f);
    tail[1] = c0; tail[2] = c1; tail[3] = c2; tail[4] = c3;
    tail[5] = c0; tail[6] = c1; tail[7] = c2; tail[8] = c3;
  }
}

// Weights -> bf16 MFMA layouts. Conv banks + GEMM banks both in
// contiguous-fragment layouts.
__global__ void k_prep(const float* __restrict__ cd, const float* __restrict__ sh,
                       const float* __restrict__ bayar,
                       const float* __restrict__ W2, const float* __restrict__ W3,
                       short* __restrict__ Wb0, short* __restrict__ WbS,
                       short* __restrict__ Wb1,
                       short* __restrict__ W2b, short* __restrict__ W3b) {
  int tid = blockIdx.x * 256 + threadIdx.x;   // o*128 + i
  if (tid >= C_ * C_) return;
  int o = tid >> 7, i = tid & 127;
  const float* c9 = cd + (size_t)tid * 9;
  const float* s9 = sh + (size_t)tid * 9;
  float s = 0.f;
#pragma unroll
  for (int k = 0; k < 9; ++k) s += c9[k];
#pragma unroll
  for (int k = 0; k < 9; ++k) {
    float w0 = c9[k] + s9[k] - (k == 4 ? 0.7f * s : 0.f);
    size_t a = waddr(9, k, o, i);
    Wb0[a] = (short)f2bf(w0);
    WbS[a] = (short)f2bf(s9[k]);
  }
  const float* r = bayar + (size_t)tid * 24;
  float rs = 0.f;
#pragma unroll
  for (int k = 0; k < 24; ++k) rs += r[k];
  float inv = 1.f / rs;
  float k25[25];
#pragma unroll
  for (int k = 0; k < 12; ++k) k25[k] = r[k] * inv;
  k25[12] = -1.f;
#pragma unroll
  for (int k = 0; k < 12; ++k) k25[13 + k] = r[12 + k] * inv;
#pragma unroll
  for (int ky = 0; ky < 3; ++ky)
#pragma unroll
    for (int kx = 0; kx < 3; ++kx)
      k25[(ky + 1) * 5 + (kx + 1)] += s9[ky * 3 + kx];
#pragma unroll
  for (int k = 0; k < 25; ++k)
    Wb1[waddr(25, k, o, i)] = (short)f2bf(k25[k]);

  // srm/hf GEMM A banks, contiguous-frag layout. k = 4c+j (j<3 srm, j=3 hf);
  // the 4 shorts 4c..4c+3 stay consecutive in one lane slot:
  //   addr = (co>>4)*8192 + (c>>3)*512 + (((c&7)>>1)*16 + (co&15))*8 + 4*(c&1)
  int co = o, c = i;
  size_t ga = (size_t)(co >> 4) * 8192 + (size_t)(c >> 3) * 512 +
              (size_t)((((c & 7) >> 1) * 16) + (co & 15)) * 8 + (size_t)((c & 1) * 4);
  const float* sp = W2 + (size_t)co * 384 + c * 3;
  unsigned long long w2 = (unsigned long long)f2bf(sp[0])
                        | ((unsigned long long)f2bf(sp[1]) << 16)
                        | ((unsigned long long)f2bf(sp[2]) << 32);
  *(unsigned long long*)(W2b + ga) = w2;
  unsigned long long w3 = ((unsigned long long)f2bf(W3[(size_t)co * 128 + c]) << 48);
  *(unsigned long long*)(W3b + ga) = w3;
}

// SRM + HF: depthwise separable filters + DPP taps; GEMM with CONTIGUOUS
// A-fragment wave-loads (1KB blocks, streaming).
__global__ __launch_bounds__(512, 4) void k_srmhf(
    const float* __restrict__ x, const short* __restrict__ W2b,
    const short* __restrict__ W3b, const int* __restrict__ top1,
    float* __restrict__ partial, float* ybuf) {
  __shared__ __align__(16) char zl[65536];
  int orig = blockIdx.x;                      // 1792 = 8 * 224
  int wgid = (orig & 7) * 224 + (orig >> 3);
  int b = wgid / 56, h0 = wgid % 56;
  int t = threadIdx.x;
  int l = t & 63, wv = t >> 6;
  const float* xb = x + (size_t)b * C_ * HW_;

  int w_ = l - 2;
  bool wok = (w_ >= 0) & (w_ < 56);
  bool px_ok = (l >= 2) & (l < 58);

  int xoff[5]; bool rok[5];
#pragma unroll
  for (int dy = 0; dy < 5; ++dy) {
    int hh = h0 - 2 + dy;
    rok[dy] = (hh >= 0) & (hh < 56) & wok;
    xoff[dy] = hh * 56 + w_;
  }

#pragma unroll 2
  for (int c = wv; c < C_; c += 8) {
    const float* xc = xb + (size_t)c * HW_;
    float rr[5];
#pragma unroll
    for (int dy = 0; dy < 5; ++dy) {
      float vv = 0.f;
      if (rok[dy]) vv = xc[xoff[dy]];
      rr[dy] = vv;
    }
    float U  = rr[0] + rr[4] + 2.f * rr[2] - 2.f * (rr[1] + rr[3]);
    float Wv = rr[1] + rr[3] - 2.f * rr[2];
    float Sv = rr[1] + rr[2] + rr[3];
    float T  = rr[2];
    float Um1 = dppf<0x138>(U),   Up1 = dppf<0x130>(U);
    float Um2 = dppf<0x138>(Um1), Up2 = dppf<0x130>(Up1);
    float Wm1 = dppf<0x138>(Wv),  Wp1 = dppf<0x130>(Wv);
    float Tm1 = dppf<0x138>(T),   Tp1 = dppf<0x130>(T);
    float Sm1 = dppf<0x138>(Sv),  Sp1 = dppf<0x130>(Sv);
    float Uh = Um2 + Up2 + 2.f * U - 2.f * (Um1 + Up1);
    float Wh = Wm1 + Wp1 - 2.f * Wv;
    float Th = Tm1 + Tp1 - 2.f * T;
    float Sh = Sm1 + Sv + Sp1;
    float s1 = -0.25f * Wh;
    float s2 = (-1.f / 12.f) * (Uh + 2.f * Wh);
    float s3 = 0.5f * Th;
    float lp = 9.f * T - Sh;
    if (px_ok) {
      int px = l - 2;
      uint32_t lo = cvtpk(fminf(fmaxf(s1, -3.f), 3.f),
                          fminf(fmaxf(s2, -3.f), 3.f));
      uint32_t hi = cvtpk(fminf(fmaxf(s3, -3.f), 3.f), lp);
      int byte = ((px << 10) + (c << 3)) ^ ((px & 7) << 4);
      *(unsigned long long*)(zl + byte) =
          (unsigned long long)lo | ((unsigned long long)hi << 32);
    }
  }

  // GEMM: 8 waves x 16 co, 4 px-frags, shared B; A-streams now CONTIGUOUS:
  // wave wv reads blocks [wv*8192 + kblk*512 + l*8], kblk = k0>>5.
  int lr = l & 15, lk = l >> 4;
  int co0 = wv * 16;
  f32x4 a2[4], a3[4];
#pragma unroll
  for (int n = 0; n < 4; ++n) {
    a2[n] = (f32x4){0.f, 0.f, 0.f, 0.f};
    a3[n] = (f32x4){0.f, 0.f, 0.f, 0.f};
  }
  const short* pA2 = W2b + (size_t)wv * 8192 + (size_t)l * 8;
  const short* pA3 = W3b + (size_t)wv * 8192 + (size_t)l * 8;
  short8v A2a = *(const short8v*)(pA2 + 0);
  short8v A3a = *(const short8v*)(pA3 + 0);
  short8v A2b = *(const short8v*)(pA2 + 512);
  short8v A3b = *(const short8v*)(pA3 + 512);
  __syncthreads();
#pragma unroll
  for (int k0 = 0; k0 < 512; k0 += 64) {
    short8v A2c = A2a, A3c = A3a, A2d = A2b, A3d = A3b;
    if (k0 + 64 < 512) {
      int nb = (k0 >> 5) * 512 + 1024;       // next block pair
      A2a = *(const short8v*)(pA2 + nb);
      A3a = *(const short8v*)(pA3 + nb);
      A2b = *(const short8v*)(pA2 + nb + 512);
      A3b = *(const short8v*)(pA3 + nb + 512);
    }
#pragma unroll
    for (int nf = 0; nf < 4; ++nf) {
      int px = nf * 16 + lr;
      int byte0 = (px * 1024 + (k0 + lk * 8) * 2) ^ ((px & 7) << 4);
      short8v Bf0 = *(const short8v*)(zl + byte0);
      a2[nf] = __builtin_amdgcn_mfma_f32_16x16x32_bf16(A2c, Bf0, a2[nf], 0, 0, 0);
      a3[nf] = __builtin_amdgcn_mfma_f32_16x16x32_bf16(A3c, Bf0, a3[nf], 0, 0, 0);
      int byte1 = (px * 1024 + (k0 + 32 + lk * 8) * 2) ^ ((px & 7) << 4);
      short8v Bf1 = *(const short8v*)(zl + byte1);
      a2[nf] = __builtin_amdgcn_mfma_f32_16x16x32_bf16(A2d, Bf1, a2[nf], 0, 0, 0);
      a3[nf] = __builtin_amdgcn_mfma_f32_16x16x32_bf16(A3d, Bf1, a3[nf], 0, 0, 0);
    }
  }

  int e = top1[b];
  if (e == 2) {
#pragma unroll
    for (int r = 0; r < 4; ++r) {
      int co = co0 + lk * 4 + r;
      float* yp = ybuf + ((size_t)(b * C_ + co)) * HW_ + h0 * 56;
#pragma unroll
      for (int nf = 0; nf < 4; ++nf) {
        int px = nf * 16 + lr;
        if (px < 56) yp[px] = a2[nf][r];
      }
    }
  } else if (e == 3) {
#pragma unroll
    for (int r = 0; r < 4; ++r) {
      int co = co0 + lk * 4 + r;
      float* yp = ybuf + ((size_t)(b * C_ + co)) * HW_ + h0 * 56;
#pragma unroll
      for (int nf = 0; nf < 4; ++nf) {
        int px = nf * 16 + lr;
        if (px < 56) yp[px] = a3[nf][r];
      }
    }
  }

  float* pb = partial + (size_t)(wgid >> 1) * 512;
#pragma unroll
  for (int r = 0; r < 4; ++r) {
    int co = co0 + lk * 4 + r;
    float s2v = 0.f, q2v = 0.f, s3v = 0.f, q3v = 0.f;
#pragma unroll
    for (int nf = 0; nf < 4; ++nf) {
      int px = nf * 16 + lr;
      float w2 = (px < 56) ? a2[nf][r] : 0.f;
      float w3 = (px < 56) ? a3[nf][r] : 0.f;
      s2v += w2; q2v += w2 * w2;
      s3v += w3; q3v += w3 * w3;
    }
    s2v = rsum16(s2v); q2v = rsum16(q2v);
    s3v = rsum16(s3v); q3v = rsum16(q3v);
    if (lr == 0) {
      atomicAdd(&pb[co], s2v);
      atomicAdd(&pb[128 + co], q2v);
      atomicAdd(&pb[256 + co], s3v);
      atomicAdd(&pb[384 + co], q3v);
    }
  }
}

// Reduce partial[896][512] -> stats[512].
__global__ void k_bn2(const float* __restrict__ partial, float* __restrict__ stats) {
  __shared__ float red[4][64];
  int lane = threadIdx.x & 63, wv = threadIdx.x >> 6;
  int entry = blockIdx.x * 64 + lane;
  float s = 0.f;
  for (int j = 0; j < 224; ++j)
    s += partial[(size_t)(wv * 224 + j) * 512 + entry];
  red[wv][lane] = s;
  __syncthreads();
  if (wv == 0)
    stats[entry] = red[0][lane] + red[1][lane] + red[2][lane] + red[3][lane];
}

__global__ void k_bn(const float* __restrict__ stats,
                     const float* __restrict__ g2, const float* __restrict__ b2,
                     const float* __restrict__ g3, const float* __restrict__ b3,
                     float* __restrict__ bn) {
  int c = threadIdx.x;
  if (c >= 128) return;
  const float n = (float)(B_ * HW_);
  float m2 = stats[c] / n, v2 = stats[128 + c] / n - m2 * m2;
  float sc2 = g2[c] * rsqrtf(v2 + 1e-5f);
  bn[c] = sc2; bn[128 + c] = b2[c] - m2 * sc2;
  float m3 = stats[256 + c] / n, v3 = stats[384 + c] / n - m3 * m3;
  float sc3 = g3[c] * rsqrtf(v3 + 1e-5f);
  bn[256 + c] = sc3; bn[384 + c] = b3[c] - m3 * sc3;
}

// ---------------- MFMA implicit-GEMM conv (contiguous weight loads) --------
template <int KS>
__device__ __forceinline__ void conv_path(const float* __restrict__ xb,
                                          const short* __restrict__ Wb,
                                          char* ldsb, int h0, int t,
                                          f32x4 (&acc)[4][7]) {
  constexpr int PAD = KS / 2;
  constexpr int RN = 4 + 2 * PAD;       // staged input rows
  constexpr int NPOS = RN * 60;
  constexpr int NTAP = KS * KS;
  int l = t & 63, wv = t >> 6;
  int cg = wv & 1, pg = wv >> 1;
  int lr = l & 15, lk = l >> 4;

  int prow[7], pcol[7];
#pragma unroll
  for (int nf = 0; nf < 7; ++nf) {
    int px = pg * 112 + nf * 16 + lr;   // 0..223
    prow[nf] = px / 56;
    pcol[nf] = px % 56;
  }

  for (int ci0 = 0; ci0 < 128; ci0 += 64) {
    __syncthreads();
    for (int idx = t; idx < NPOS * 8; idx += 256) {
      int pos = idx % NPOS;
      int cig = idx / NPOS;
      int row = pos / 60, col = pos % 60;
      int h_in = h0 - PAD + row, w_in = col - 2;
      bool ok = (h_in >= 0) & (h_in < 56) & (w_in >= 0) & (w_in < 56);
      const float* xp = xb + (size_t)(ci0 + cig * 8) * HW_ + h_in * 56 + w_in;
      float f[8];
#pragma unroll
      for (int i2 = 0; i2 < 8; ++i2) f[i2] = ok ? xp[i2 * HW_] : 0.f;
      u32x4 pk;
      pk.x = cvtpk(f[0], f[1]);
      pk.y = cvtpk(f[2], f[3]);
      pk.z = cvtpk(f[4], f[5]);
      pk.w = cvtpk(f[6], f[7]);
      int byte = pos * 128 + cig * 16;
      byte ^= (pos & 7) << 4;
      *(u32x4*)(ldsb + byte) = pk;
    }

    // Contiguous weight base: frag f at +f*512, tap at +tap*8192 (shorts).
    const short* wbase = Wb + (size_t)(ci0 >> 6) * ((size_t)NTAP * 8192) +
                         (size_t)cg * 4096 + (size_t)l * 8;
    short8v At[8];
#pragma unroll
    for (int f = 0; f < 8; ++f)
      At[f] = *(const short8v*)(wbase + f * 512);
    __syncthreads();

    for (int tap = 0; tap < NTAP; ++tap) {
      short8v cur[8];
#pragma unroll
      for (int i = 0; i < 8; ++i) cur[i] = At[i];
      if (tap + 1 < NTAP) {
        const short* wtn = wbase + (size_t)(tap + 1) * 8192;
#pragma unroll
        for (int f = 0; f < 8; ++f)
          At[f] = *(const short8v*)(wtn + f * 512);
      }
      int dy = tap / KS, dx = tap % KS;
      int posb[7];
#pragma unroll
      for (int nf = 0; nf < 7; ++nf)
        posb[nf] = (prow[nf] + dy) * 60 + pcol[nf] + dx - PAD + 2;
#pragma unroll
      for (int hh = 0; hh < 2; ++hh) {
        int kb = (hh * 32 + lk * 8) * 2;
#pragma unroll
        for (int nf = 0; nf < 7; ++nf) {
          int byte = (posb[nf] * 128 + kb) ^ ((posb[nf] & 7) << 4);
          short8v bf = *(const short8v*)(ldsb + byte);
          acc[0][nf] = __builtin_amdgcn_mfma_f32_16x16x32_bf16(cur[hh * 4 + 0], bf, acc[0][nf], 0, 0, 0);
          acc[1][nf] = __builtin_amdgcn_mfma_f32_16x16x32_bf16(cur[hh * 4 + 1], bf, acc[1][nf], 0, 0, 0);
          acc[2][nf] = __builtin_amdgcn_mfma_f32_16x16x32_bf16(cur[hh * 4 + 2], bf, acc[2][nf], 0, 0, 0);
          acc[3][nf] = __builtin_amdgcn_mfma_f32_16x16x32_bf16(cur[hh * 4 + 3], bf, acc[3][nf], 0, 0, 0);
        }
      }
    }
  }
}

__global__ __launch_bounds__(256, 2) void k_main(
    const float* __restrict__ x, const short* __restrict__ Wb0,
    const short* __restrict__ WbS, const short* __restrict__ Wb1,
    const float* __restrict__ bn, const int* __restrict__ top1, float* out) {
  __shared__ __align__(16) char ldsb[61440];
  int orig = blockIdx.x;                       // 448 blocks, bijective XCD swizzle
  int wgid = (orig & 7) * 56 + (orig >> 3);
  int b = wgid / 14;
  int h0 = (wgid % 14) * 4;
  int e = top1[b];
  const float* xb = x + (size_t)b * C_ * HW_;
  int t = threadIdx.x;

  f32x4 acc[4][7];
#pragma unroll
  for (int m = 0; m < 4; ++m)
#pragma unroll
    for (int n = 0; n < 7; ++n) acc[m][n] = (f32x4){0.f, 0.f, 0.f, 0.f};

  if (e == 1) conv_path<5>(xb, Wb1, ldsb, h0, t, acc);
  else        conv_path<3>(xb, (e == 0) ? Wb0 : WbS, ldsb, h0, t, acc);

  int l = t & 63, wv = t >> 6;
  int cg = wv & 1, pg = wv >> 1;
  int lr = l & 15, lk = l >> 4;
  bool post = (e >= 2);
  const float* sc = bn + (e == 3 ? 256 : 0);
  const float* bi = sc + 128;
#pragma unroll
  for (int mf = 0; mf < 4; ++mf) {
#pragma unroll
    for (int rr = 0; rr < 4; ++rr) {
      int co = cg * 64 + mf * 16 + lk * 4 + rr;
      float s = post ? sc[co] : 0.f;
      float bb = post ? bi[co] : 0.f;
      float* orow = out + ((size_t)(b * C_ + co)) * HW_;
#pragma unroll
      for (int nf = 0; nf < 7; ++nf) {
        int px = pg * 112 + nf * 16 + lr;
        int rg = px / 56, c = px % 56;
        size_t idx = (size_t)(h0 + rg) * 56 + c;
        float v = acc[mf][nf][rr];
        if (post) v += fmaxf(0.f, s * orow[idx] + bb);
        orow[idx] = v;
      }
    }
  }
}

extern "C" void kernel_launch(void* const* d_in, const int* in_sizes, int n_in,
                              void* d_out, int out_size, void* d_ws, size_t ws_size,
                              hipStream_t stream) {
  const float* x        = (const float*)d_in[0];
  const float* Wg       = (const float*)d_in[1];
  const float* cd_w     = (const float*)d_in[2];
  const float* bayar_w  = (const float*)d_in[3];
  const float* srm_out  = (const float*)d_in[5];
  const float* srm_g    = (const float*)d_in[6];
  const float* srm_b    = (const float*)d_in[7];
  const float* hf_out   = (const float*)d_in[9];
  const float* hf_g     = (const float*)d_in[10];
  const float* hf_b     = (const float*)d_in[11];
  const float* shared_w = (const float*)d_in[12];

  char* wsb      = (char*)d_ws;
  float* pooled  = (float*)wsb;                 // 16384 B
  int*   top1    = (int*)(wsb + 16384);         // 128 B
  float* stats   = (float*)(wsb + 16512);       // 2048 B
  float* bn      = (float*)(wsb + 18560);       // 2048 B
  short* Wb0     = (short*)(wsb + 20608);       // 294912 B
  short* WbS     = (short*)(wsb + 315520);      // 294912 B
  short* Wb1     = (short*)(wsb + 610432);      // 819200 B
  short* Wb2     = (short*)(wsb + 1429632);     // 131072 B
  short* Wb3     = (short*)(wsb + 1560704);     // 131072 B
  float* partial = (float*)(wsb + 1691776);     // 1835008 B -> ends 3526784

  float* out  = (float*)d_out;
  float* tail = out + (size_t)12845056;

  hipMemsetAsync(partial, 0, 1835008, stream);
  k_pool<<<B_ * C_, 256, 0, stream>>>(x, pooled);
  k_gate<<<1, 64, 0, stream>>>(pooled, Wg, top1, tail);
  k_prep<<<64, 256, 0, stream>>>(cd_w, shared_w, bayar_w, srm_out, hf_out,
                                 Wb0, WbS, Wb1, Wb2, Wb3);
  k_srmhf<<<1792, 512, 0, stream>>>(x, Wb2, Wb3, top1, partial, out);
  k_bn2<<<8, 256, 0, stream>>>(partial, stats);
  k_bn<<<1, 128, 0, stream>>>(stats, srm_g, srm_b, hf_g, hf_b, bn);
  k_main<<<448, 256, 0, stream>>>(x, Wb0, WbS, Wb1, bn, top1, out);
}